// Round 2
// baseline (658.020 us; speedup 1.0000x reference)
//
#include <hip/hip_runtime.h>

#define TT 2048
#define BB 1024
#define H  10

// One wave64 per sequence. Self-dot design: no DS ops anywhere.
// Lanes 0-9  : layer-0 gate lane for unit u = l      (consumes sh1 = h1_{i-1}, x_i)
// Lanes 10-19: layer-1 gate lane for unit u = l-10   (consumes sh1 = h1_{i-1}, sh2 = h2_{i-2})
// Lane  20   : output head: dotR = blin + Wlin . sh2 (= h2_{i-2}) -> out[t], t = i-2
// Hidden state is wave-uniform: S[0..9] = h1_{i-1}, S[10..19] = h2_{i-2}, held in
// SGPRs via v_readlane; every gate lane computes its r/z/n dots itself against S.
// Weights pre-scaled by -log2(e) (r,z rows) and +2*log2(e) (n rows) so sigmoids and
// tanh use raw v_exp_f32 (exp2) with no chain-side multiply:
//   r = rcp(1 + 2^(dotR)),  z = rcp(1 + 2^(dotZ))          [dots pre-negated+scaled]
//   q = fma(r, dotNh, dotNx);  n = 1 - 2*rcp(1 + 2^q)
//   h' = (1-z)*n + z*h  =  fma(z, hprev, fma(-z, n, n))

__device__ __forceinline__ float exp2f_fast(float a) {
    return __builtin_amdgcn_exp2f(a);
}
__device__ __forceinline__ float rcpf_fast(float a) {
    return __builtin_amdgcn_rcpf(a);
}

__global__ __launch_bounds__(64) void gru_wave_kernel(
    const float* __restrict__ X,
    const float* __restrict__ Wih0, const float* __restrict__ Whh0,
    const float* __restrict__ bih0, const float* __restrict__ bhh0,
    const float* __restrict__ Wih1, const float* __restrict__ Whh1,
    const float* __restrict__ bih1, const float* __restrict__ bhh1,
    const float* __restrict__ Wlin, const float* __restrict__ blin,
    float* __restrict__ OUT)
{
    const int seq = blockIdx.x;
    const int l   = threadIdx.x;   // 0..63
    const float L2E = 1.44269504088896340736f;

    // per-lane weights over the 20-vector S = [sh1(10); sh2(10)]
    float wR[20], wZ[20], wNh[20], wNx[10];
    float bR = 0.f, bZ = 0.f, bNh = 0.f, bNx = 0.f;
    float wxr = 0.f, wxz = 0.f, wxn = 0.f;
    #pragma unroll
    for (int k = 0; k < 20; ++k) { wR[k] = 0.f; wZ[k] = 0.f; wNh[k] = 0.f; }
    #pragma unroll
    for (int k = 0; k < 10; ++k) wNx[k] = 0.f;

    if (l < 10) {                       // layer-0 gate lane, unit u = l
        const int u = l;
        #pragma unroll
        for (int k = 0; k < H; ++k) {
            wR[k]  = -L2E * Whh0[u * H + k];
            wZ[k]  = -L2E * Whh0[(10 + u) * H + k];
            wNh[k] = 2.f * L2E * Whh0[(20 + u) * H + k];
        }
        bR  = -L2E * (bih0[u] + bhh0[u]);
        bZ  = -L2E * (bih0[10 + u] + bhh0[10 + u]);
        bNh = 2.f * L2E * bhh0[20 + u];
        bNx = 2.f * L2E * bih0[20 + u];
        wxr = -L2E * Wih0[u];
        wxz = -L2E * Wih0[10 + u];
        wxn = 2.f * L2E * Wih0[20 + u];
    } else if (l < 20) {                // layer-1 gate lane, unit u = l-10
        const int u = l - 10;
        #pragma unroll
        for (int k = 0; k < H; ++k) {
            wR[k]       = -L2E * Wih1[u * H + k];          // x sh1
            wR[10 + k]  = -L2E * Whh1[u * H + k];          // x sh2
            wZ[k]       = -L2E * Wih1[(10 + u) * H + k];
            wZ[10 + k]  = -L2E * Whh1[(10 + u) * H + k];
            wNh[10 + k] = 2.f * L2E * Whh1[(20 + u) * H + k];
            wNx[k]      = 2.f * L2E * Wih1[(20 + u) * H + k];
        }
        bR  = -L2E * (bih1[u] + bhh1[u]);
        bZ  = -L2E * (bih1[10 + u] + bhh1[10 + u]);
        bNh = 2.f * L2E * bhh1[20 + u];
        bNx = 2.f * L2E * bih1[20 + u];
    } else if (l == 20) {               // output head: raw (unscaled) dotR = out
        #pragma unroll
        for (int k = 0; k < H; ++k) wR[10 + k] = Wlin[k];
        bR = blin[0];
    }

    const bool isL1g = (l >= 10 && l < 20);
    const bool is20  = (l == 20);

    // wave-uniform state in SGPRs: S[0..9] = h1_{i-1}, S[10..19] = h2_{i-2}
    float S[20];
    #pragma unroll
    for (int k = 0; k < 20; ++k) S[k] = 0.f;

    float hprev = 0.f;   // gate lane's own previous hidden value

    const float* xp = X + seq * TT;
    float*       op = OUT + seq * TT;

    float4 xq = *(const float4*)xp;   // x block 0, prefetched

    for (int ib = 0; ib < 513; ++ib) {
        int nb = 4 * (ib + 1);
        if (nb > TT - 4) nb = TT - 4;
        float4 xqn = *(const float4*)(xp + nb);   // prefetch next x block
        float xs[4] = {xq.x, xq.y, xq.z, xq.w};
        #pragma unroll
        for (int u4 = 0; u4 < 4; ++u4) {
            const float x = xs[u4];

            // dotR: 4 split chains of 5 (x-term seeds chain 0)
            float r0 = fmaf(wxr, x, bR);
            float r1 = wR[5]  * S[5];
            float r2 = wR[10] * S[10];
            float r3 = wR[15] * S[15];
            r0 = fmaf(wR[0], S[0], r0);  r1 = fmaf(wR[6], S[6], r1);
            r2 = fmaf(wR[11], S[11], r2); r3 = fmaf(wR[16], S[16], r3);
            r0 = fmaf(wR[1], S[1], r0);  r1 = fmaf(wR[7], S[7], r1);
            r2 = fmaf(wR[12], S[12], r2); r3 = fmaf(wR[17], S[17], r3);
            r0 = fmaf(wR[2], S[2], r0);  r1 = fmaf(wR[8], S[8], r1);
            r2 = fmaf(wR[13], S[13], r2); r3 = fmaf(wR[18], S[18], r3);
            r0 = fmaf(wR[3], S[3], r0);  r1 = fmaf(wR[9], S[9], r1);
            r2 = fmaf(wR[14], S[14], r2); r3 = fmaf(wR[19], S[19], r3);
            r0 = fmaf(wR[4], S[4], r0);
            float dotR = (r0 + r1) + (r2 + r3);

            // dotZ
            float z0 = fmaf(wxz, x, bZ);
            float z1 = wZ[5]  * S[5];
            float z2 = wZ[10] * S[10];
            float z3 = wZ[15] * S[15];
            z0 = fmaf(wZ[0], S[0], z0);  z1 = fmaf(wZ[6], S[6], z1);
            z2 = fmaf(wZ[11], S[11], z2); z3 = fmaf(wZ[16], S[16], z3);
            z0 = fmaf(wZ[1], S[1], z0);  z1 = fmaf(wZ[7], S[7], z1);
            z2 = fmaf(wZ[12], S[12], z2); z3 = fmaf(wZ[17], S[17], z3);
            z0 = fmaf(wZ[2], S[2], z0);  z1 = fmaf(wZ[8], S[8], z1);
            z2 = fmaf(wZ[13], S[13], z2); z3 = fmaf(wZ[18], S[18], z3);
            z0 = fmaf(wZ[3], S[3], z0);  z1 = fmaf(wZ[9], S[9], z1);
            z2 = fmaf(wZ[14], S[14], z2); z3 = fmaf(wZ[19], S[19], z3);
            z0 = fmaf(wZ[4], S[4], z0);
            float dotZ = (z0 + z1) + (z2 + z3);

            // dotNh (hidden part of n-gate, pre-scaled by 2*log2e)
            float n0 = fmaf(wNh[0], S[0], bNh);
            float n1 = wNh[5]  * S[5];
            float n2 = wNh[10] * S[10];
            float n3 = wNh[15] * S[15];
            n0 = fmaf(wNh[1], S[1], n0);  n1 = fmaf(wNh[6], S[6], n1);
            n2 = fmaf(wNh[11], S[11], n2); n3 = fmaf(wNh[16], S[16], n3);
            n0 = fmaf(wNh[2], S[2], n0);  n1 = fmaf(wNh[7], S[7], n1);
            n2 = fmaf(wNh[12], S[12], n2); n3 = fmaf(wNh[17], S[17], n3);
            n0 = fmaf(wNh[3], S[3], n0);  n1 = fmaf(wNh[8], S[8], n1);
            n2 = fmaf(wNh[13], S[13], n2); n3 = fmaf(wNh[18], S[18], n3);
            n0 = fmaf(wNh[4], S[4], n0);  n1 = fmaf(wNh[9], S[9], n1);
            n2 = fmaf(wNh[14], S[14], n2); n3 = fmaf(wNh[19], S[19], n3);
            float dotNh = (n0 + n1) + (n2 + n3);

            // dotNx (input part of n-gate; L0 uses x-term, L1 a dot over sh1)
            float q0 = fmaf(wxn, x, bNx);
            float q1 = wNx[5] * S[5];
            q0 = fmaf(wNx[0], S[0], q0); q1 = fmaf(wNx[6], S[6], q1);
            q0 = fmaf(wNx[1], S[1], q0); q1 = fmaf(wNx[7], S[7], q1);
            q0 = fmaf(wNx[2], S[2], q0); q1 = fmaf(wNx[8], S[8], q1);
            q0 = fmaf(wNx[3], S[3], q0); q1 = fmaf(wNx[9], S[9], q1);
            q0 = fmaf(wNx[4], S[4], q0);
            float dotNx = q0 + q1;

            // gates (dots already scaled: r/z by -log2e, n by 2*log2e)
            float r = rcpf_fast(1.0f + exp2f_fast(dotR));
            float z = rcpf_fast(1.0f + exp2f_fast(dotZ));
            float q = fmaf(r, dotNh, dotNx);
            float n = fmaf(-2.0f, rcpf_fast(1.0f + exp2f_fast(q)), 1.0f);
            float hnew = fmaf(z, hprev, fmaf(-z, n, n));

            // iteration 0: L1 gate lanes would publish garbage h2_{-1}; force 0
            if (ib == 0 && u4 == 0) { if (isL1g) hnew = 0.f; }
            hprev = hnew;

            // publish wave-uniform state (lanes 0-9 -> sh1, 10-19 -> sh2)
            int hbits = __float_as_int(hnew);
            #pragma unroll
            for (int k = 0; k < 20; ++k)
                S[k] = __int_as_float(__builtin_amdgcn_readlane(hbits, k));

            // output head: lane 20's raw dotR = blin + Wlin . h2_{i-2}
            const int t = (ib * 4 + u4) - 2;
            if (is20 && (unsigned)t < TT) op[t] = dotR;
        }
        xq = xqn;
    }
}

extern "C" void kernel_launch(void* const* d_in, const int* in_sizes, int n_in,
                              void* d_out, int out_size, void* d_ws, size_t ws_size,
                              hipStream_t stream) {
    const float* X    = (const float*)d_in[0];
    const float* Wih0 = (const float*)d_in[1];
    const float* Whh0 = (const float*)d_in[2];
    const float* bih0 = (const float*)d_in[3];
    const float* bhh0 = (const float*)d_in[4];
    const float* Wih1 = (const float*)d_in[5];
    const float* Whh1 = (const float*)d_in[6];
    const float* bih1 = (const float*)d_in[7];
    const float* bhh1 = (const float*)d_in[8];
    const float* Wlin = (const float*)d_in[9];
    const float* blin = (const float*)d_in[10];

    gru_wave_kernel<<<BB, 64, 0, stream>>>(X, Wih0, Whh0, bih0, bhh0,
                                           Wih1, Whh1, bih1, bhh1, Wlin, blin,
                                           (float*)d_out);
}

// Round 3
// 567.078 us; speedup vs baseline: 1.1604x; 1.1604x over previous
//
#include <hip/hip_runtime.h>

#define TT 2048
#define BB 1024
#define H  10

// One wave64 per sequence. Self-dot design: no DS ops anywhere.
// Lanes 0-9  : layer-0 gate lane for unit u = l      (consumes sh1 = h1_{i-1}, x_i)
// Lanes 10-19: layer-1 gate lane for unit u = l-10   (consumes sh1 = h1_{i-1}, sh2 = h2_{i-2})
// Lane  20   : output head: dotR = blin + Wlin . sh2 (= h2_{i-2}) -> out[t], t = i-2
// State is wave-uniform in SGPRs (20 v_readlane/step); weights per-lane in VGPRs.
// __launch_bounds__(64, 1): 1 wave/SIMD target -> VGPR cap 512. Round-2's
// plain __launch_bounds__(64) let the compiler pick 48 VGPRs and spill the
// 70-element weight arrays to scratch (723 cyc/step). ~110 VGPRs needed.
// Weights pre-scaled by -log2(e) (r,z rows) and +2*log2(e) (n rows):
//   r = rcp(1 + 2^dotR),  z = rcp(1 + 2^dotZ)
//   q = fma(r, dotNh, dotNx);  n = 1 - 2*rcp(1 + 2^q)
//   h' = fma(z, hprev, fma(-z, n, n))

__device__ __forceinline__ float exp2f_fast(float a) {
    return __builtin_amdgcn_exp2f(a);
}
__device__ __forceinline__ float rcpf_fast(float a) {
    return __builtin_amdgcn_rcpf(a);
}

__global__ __launch_bounds__(64, 1) void gru_wave_kernel(
    const float* __restrict__ X,
    const float* __restrict__ Wih0, const float* __restrict__ Whh0,
    const float* __restrict__ bih0, const float* __restrict__ bhh0,
    const float* __restrict__ Wih1, const float* __restrict__ Whh1,
    const float* __restrict__ bih1, const float* __restrict__ bhh1,
    const float* __restrict__ Wlin, const float* __restrict__ blin,
    float* __restrict__ OUT)
{
    const int seq = blockIdx.x;
    const int l   = threadIdx.x;   // 0..63
    const float L2E = 1.44269504088896340736f;

    // per-lane weights over the 20-vector S = [sh1(10); sh2(10)]
    float wR[20], wZ[20], wNh[20], wNx[10];
    float bR = 0.f, bZ = 0.f, bNh = 0.f, bNx = 0.f;
    float wxr = 0.f, wxz = 0.f, wxn = 0.f;
    #pragma unroll
    for (int k = 0; k < 20; ++k) { wR[k] = 0.f; wZ[k] = 0.f; wNh[k] = 0.f; }
    #pragma unroll
    for (int k = 0; k < 10; ++k) wNx[k] = 0.f;

    if (l < 10) {                       // layer-0 gate lane, unit u = l
        const int u = l;
        #pragma unroll
        for (int k = 0; k < H; ++k) {
            wR[k]  = -L2E * Whh0[u * H + k];
            wZ[k]  = -L2E * Whh0[(10 + u) * H + k];
            wNh[k] = 2.f * L2E * Whh0[(20 + u) * H + k];
        }
        bR  = -L2E * (bih0[u] + bhh0[u]);
        bZ  = -L2E * (bih0[10 + u] + bhh0[10 + u]);
        bNh = 2.f * L2E * bhh0[20 + u];
        bNx = 2.f * L2E * bih0[20 + u];
        wxr = -L2E * Wih0[u];
        wxz = -L2E * Wih0[10 + u];
        wxn = 2.f * L2E * Wih0[20 + u];
    } else if (l < 20) {                // layer-1 gate lane, unit u = l-10
        const int u = l - 10;
        #pragma unroll
        for (int k = 0; k < H; ++k) {
            wR[k]       = -L2E * Wih1[u * H + k];          // x sh1
            wR[10 + k]  = -L2E * Whh1[u * H + k];          // x sh2
            wZ[k]       = -L2E * Wih1[(10 + u) * H + k];
            wZ[10 + k]  = -L2E * Whh1[(10 + u) * H + k];
            wNh[10 + k] = 2.f * L2E * Whh1[(20 + u) * H + k];
            wNx[k]      = 2.f * L2E * Wih1[(20 + u) * H + k];
        }
        bR  = -L2E * (bih1[u] + bhh1[u]);
        bZ  = -L2E * (bih1[10 + u] + bhh1[10 + u]);
        bNh = 2.f * L2E * bhh1[20 + u];
        bNx = 2.f * L2E * bih1[20 + u];
    } else if (l == 20) {               // output head: raw (unscaled) dotR = out
        #pragma unroll
        for (int k = 0; k < H; ++k) wR[10 + k] = Wlin[k];
        bR = blin[0];
    }

    const bool isL1g = (l >= 10 && l < 20);
    const bool is20  = (l == 20);

    // wave-uniform state in SGPRs: S[0..9] = h1_{i-1}, S[10..19] = h2_{i-2}
    float S[20];
    #pragma unroll
    for (int k = 0; k < 20; ++k) S[k] = 0.f;

    float hprev = 0.f;   // gate lane's own previous hidden value

    const float* xp = X + seq * TT;
    float*       op = OUT + seq * TT;

    float4 xq = *(const float4*)xp;   // x block 0, prefetched

    for (int ib = 0; ib < 513; ++ib) {
        int nb = 4 * (ib + 1);
        if (nb > TT - 4) nb = TT - 4;
        float4 xqn = *(const float4*)(xp + nb);   // prefetch next x block
        float xs[4] = {xq.x, xq.y, xq.z, xq.w};
        #pragma unroll
        for (int u4 = 0; u4 < 4; ++u4) {
            const float x = xs[u4];

            // dotR: 2 interleaved chains of 10
            float r0 = fmaf(wxr, x, bR);
            float r1 = wR[1] * S[1];
            r0 = fmaf(wR[0], S[0], r0);
            #pragma unroll
            for (int k = 2; k < 20; k += 2) {
                r0 = fmaf(wR[k],     S[k],     r0);
                r1 = fmaf(wR[k + 1], S[k + 1], r1);
            }
            float dotR = r0 + r1;

            // dotZ
            float z0 = fmaf(wxz, x, bZ);
            float z1 = wZ[1] * S[1];
            z0 = fmaf(wZ[0], S[0], z0);
            #pragma unroll
            for (int k = 2; k < 20; k += 2) {
                z0 = fmaf(wZ[k],     S[k],     z0);
                z1 = fmaf(wZ[k + 1], S[k + 1], z1);
            }
            float dotZ = z0 + z1;

            // dotNh (hidden part of n-gate, pre-scaled by 2*log2e)
            float n0 = fmaf(wNh[0], S[0], bNh);
            float n1 = wNh[1] * S[1];
            #pragma unroll
            for (int k = 2; k < 20; k += 2) {
                n0 = fmaf(wNh[k],     S[k],     n0);
                n1 = fmaf(wNh[k + 1], S[k + 1], n1);
            }
            float dotNh = n0 + n1;

            // dotNx (input part of n-gate; L0 uses x-term, L1 a dot over sh1)
            float q0 = fmaf(wxn, x, bNx);
            float q1 = wNx[1] * S[1];
            q0 = fmaf(wNx[0], S[0], q0);
            #pragma unroll
            for (int k = 2; k < 10; k += 2) {
                q0 = fmaf(wNx[k],     S[k],     q0);
                q1 = fmaf(wNx[k + 1], S[k + 1], q1);
            }
            float dotNx = q0 + q1;

            // gates (dots already scaled: r/z by -log2e, n by 2*log2e)
            float r = rcpf_fast(1.0f + exp2f_fast(dotR));
            float z = rcpf_fast(1.0f + exp2f_fast(dotZ));
            float q = fmaf(r, dotNh, dotNx);
            float n = fmaf(-2.0f, rcpf_fast(1.0f + exp2f_fast(q)), 1.0f);
            float hnew = fmaf(z, hprev, fmaf(-z, n, n));

            // iteration 0: L1 gate lanes would publish garbage h2_{-1}; force 0
            if (ib == 0 && u4 == 0) { if (isL1g) hnew = 0.f; }
            hprev = hnew;

            // publish wave-uniform state (lanes 0-9 -> sh1, 10-19 -> sh2)
            int hbits = __float_as_int(hnew);
            #pragma unroll
            for (int k = 0; k < 20; ++k)
                S[k] = __int_as_float(__builtin_amdgcn_readlane(hbits, k));

            // output head: lane 20's raw dotR = blin + Wlin . h2_{i-2}
            const int t = (ib * 4 + u4) - 2;
            if (is20 && (unsigned)t < TT) op[t] = dotR;
        }
        xq = xqn;
    }
}

extern "C" void kernel_launch(void* const* d_in, const int* in_sizes, int n_in,
                              void* d_out, int out_size, void* d_ws, size_t ws_size,
                              hipStream_t stream) {
    const float* X    = (const float*)d_in[0];
    const float* Wih0 = (const float*)d_in[1];
    const float* Whh0 = (const float*)d_in[2];
    const float* bih0 = (const float*)d_in[3];
    const float* bhh0 = (const float*)d_in[4];
    const float* Wih1 = (const float*)d_in[5];
    const float* Whh1 = (const float*)d_in[6];
    const float* bih1 = (const float*)d_in[7];
    const float* bhh1 = (const float*)d_in[8];
    const float* Wlin = (const float*)d_in[9];
    const float* blin = (const float*)d_in[10];

    gru_wave_kernel<<<BB, 64, 0, stream>>>(X, Wih0, Whh0, bih0, bhh0,
                                           Wih1, Whh1, bih1, bhh1, Wlin, blin,
                                           (float*)d_out);
}

// Round 4
// 564.166 us; speedup vs baseline: 1.1664x; 1.0052x over previous
//
#include <hip/hip_runtime.h>

#define TT 2048
#define BB 1024
#define H  10

// One wave64 per sequence. Self-dot design: no DS ops anywhere.
// Lanes 0-9  : layer-0 gate lane for unit u = l      (consumes sh1 = h1_{i-1}, x_i)
// Lanes 10-19: layer-1 gate lane for unit u = l-10   (consumes sh1 = h1_{i-1}, sh2 = h2_{i-2})
// Lane  20   : output head: dotR = blin + Wlin . sh2 (= h2_{i-2}) -> out[t], t = i-2
// State is wave-uniform in SGPRs (20 v_readlane/step); weights per-lane in VGPRs.
//
// amdgpu_waves_per_eu(1,1): rounds 2-3 proved __launch_bounds__(64[,1]) leaves
// the allocator targeting ~8 waves/EU (VGPR_Count=48) and spilling the 70-float
// weight arrays to scratch (~620 cyc/step). Max-occupancy=1 removes any reason
// to cap VGPRs: 1024 waves on 1024 SIMDs means 1 wave/EU is all we ever get.
//
// Weights pre-scaled by -log2(e) (r,z rows) and +2*log2(e) (n rows):
//   r = rcp(1 + 2^dotR),  z = rcp(1 + 2^dotZ)
//   q = fma(r, dotNh, dotNx);  n = 1 - 2*rcp(1 + 2^q)
//   h' = fma(z, hprev, fma(-z, n, n))

__device__ __forceinline__ float exp2f_fast(float a) {
    return __builtin_amdgcn_exp2f(a);
}
__device__ __forceinline__ float rcpf_fast(float a) {
    return __builtin_amdgcn_rcpf(a);
}

__global__ __launch_bounds__(64)
__attribute__((amdgpu_waves_per_eu(1, 1)))
void gru_wave_kernel(
    const float* __restrict__ X,
    const float* __restrict__ Wih0, const float* __restrict__ Whh0,
    const float* __restrict__ bih0, const float* __restrict__ bhh0,
    const float* __restrict__ Wih1, const float* __restrict__ Whh1,
    const float* __restrict__ bih1, const float* __restrict__ bhh1,
    const float* __restrict__ Wlin, const float* __restrict__ blin,
    float* __restrict__ OUT)
{
    const int seq = blockIdx.x;
    const int l   = threadIdx.x;   // 0..63
    const float L2E = 1.44269504088896340736f;

    // per-lane weights over the 20-vector S = [sh1(10); sh2(10)]
    float wR[20], wZ[20], wNh[20], wNx[10];
    float bR = 0.f, bZ = 0.f, bNh = 0.f, bNx = 0.f;
    float wxr = 0.f, wxz = 0.f, wxn = 0.f;
    #pragma unroll
    for (int k = 0; k < 20; ++k) { wR[k] = 0.f; wZ[k] = 0.f; wNh[k] = 0.f; }
    #pragma unroll
    for (int k = 0; k < 10; ++k) wNx[k] = 0.f;

    if (l < 10) {                       // layer-0 gate lane, unit u = l
        const int u = l;
        #pragma unroll
        for (int k = 0; k < H; ++k) {
            wR[k]  = -L2E * Whh0[u * H + k];
            wZ[k]  = -L2E * Whh0[(10 + u) * H + k];
            wNh[k] = 2.f * L2E * Whh0[(20 + u) * H + k];
        }
        bR  = -L2E * (bih0[u] + bhh0[u]);
        bZ  = -L2E * (bih0[10 + u] + bhh0[10 + u]);
        bNh = 2.f * L2E * bhh0[20 + u];
        bNx = 2.f * L2E * bih0[20 + u];
        wxr = -L2E * Wih0[u];
        wxz = -L2E * Wih0[10 + u];
        wxn = 2.f * L2E * Wih0[20 + u];
    } else if (l < 20) {                // layer-1 gate lane, unit u = l-10
        const int u = l - 10;
        #pragma unroll
        for (int k = 0; k < H; ++k) {
            wR[k]       = -L2E * Wih1[u * H + k];          // x sh1
            wR[10 + k]  = -L2E * Whh1[u * H + k];          // x sh2
            wZ[k]       = -L2E * Wih1[(10 + u) * H + k];
            wZ[10 + k]  = -L2E * Whh1[(10 + u) * H + k];
            wNh[10 + k] = 2.f * L2E * Whh1[(20 + u) * H + k];
            wNx[k]      = 2.f * L2E * Wih1[(20 + u) * H + k];
        }
        bR  = -L2E * (bih1[u] + bhh1[u]);
        bZ  = -L2E * (bih1[10 + u] + bhh1[10 + u]);
        bNh = 2.f * L2E * bhh1[20 + u];
        bNx = 2.f * L2E * bih1[20 + u];
    } else if (l == 20) {               // output head: raw (unscaled) dotR = out
        #pragma unroll
        for (int k = 0; k < H; ++k) wR[10 + k] = Wlin[k];
        bR = blin[0];
    }

    const bool isL1g = (l >= 10 && l < 20);
    const bool is20  = (l == 20);

    // wave-uniform state in SGPRs: S[0..9] = h1_{i-1}, S[10..19] = h2_{i-2}
    float S[20];
    #pragma unroll
    for (int k = 0; k < 20; ++k) S[k] = 0.f;

    float hprev = 0.f;   // gate lane's own previous hidden value

    const float* xp = X + seq * TT;
    float*       op = OUT + seq * TT;

    float4 xq = *(const float4*)xp;   // x block 0, prefetched

    for (int ib = 0; ib < 513; ++ib) {
        int nb = 4 * (ib + 1);
        if (nb > TT - 4) nb = TT - 4;
        float4 xqn = *(const float4*)(xp + nb);   // prefetch next x block
        float xs[4] = {xq.x, xq.y, xq.z, xq.w};
        #pragma unroll
        for (int u4 = 0; u4 < 4; ++u4) {
            const float x = xs[u4];

            // dotR: 2 interleaved chains of 10
            float r0 = fmaf(wxr, x, bR);
            float r1 = wR[1] * S[1];
            r0 = fmaf(wR[0], S[0], r0);
            #pragma unroll
            for (int k = 2; k < 20; k += 2) {
                r0 = fmaf(wR[k],     S[k],     r0);
                r1 = fmaf(wR[k + 1], S[k + 1], r1);
            }
            float dotR = r0 + r1;

            // dotZ
            float z0 = fmaf(wxz, x, bZ);
            float z1 = wZ[1] * S[1];
            z0 = fmaf(wZ[0], S[0], z0);
            #pragma unroll
            for (int k = 2; k < 20; k += 2) {
                z0 = fmaf(wZ[k],     S[k],     z0);
                z1 = fmaf(wZ[k + 1], S[k + 1], z1);
            }
            float dotZ = z0 + z1;

            // dotNh (hidden part of n-gate, pre-scaled by 2*log2e)
            float n0 = fmaf(wNh[0], S[0], bNh);
            float n1 = wNh[1] * S[1];
            #pragma unroll
            for (int k = 2; k < 20; k += 2) {
                n0 = fmaf(wNh[k],     S[k],     n0);
                n1 = fmaf(wNh[k + 1], S[k + 1], n1);
            }
            float dotNh = n0 + n1;

            // dotNx (input part of n-gate; L0 uses x-term, L1 a dot over sh1)
            float q0 = fmaf(wxn, x, bNx);
            float q1 = wNx[1] * S[1];
            q0 = fmaf(wNx[0], S[0], q0);
            #pragma unroll
            for (int k = 2; k < 10; k += 2) {
                q0 = fmaf(wNx[k],     S[k],     q0);
                q1 = fmaf(wNx[k + 1], S[k + 1], q1);
            }
            float dotNx = q0 + q1;

            // gates (dots already scaled: r/z by -log2e, n by 2*log2e)
            float r = rcpf_fast(1.0f + exp2f_fast(dotR));
            float z = rcpf_fast(1.0f + exp2f_fast(dotZ));
            float q = fmaf(r, dotNh, dotNx);
            float n = fmaf(-2.0f, rcpf_fast(1.0f + exp2f_fast(q)), 1.0f);
            float hnew = fmaf(z, hprev, fmaf(-z, n, n));

            // iteration 0: L1 gate lanes would publish garbage h2_{-1}; force 0
            if (ib == 0 && u4 == 0) { if (isL1g) hnew = 0.f; }
            hprev = hnew;

            // publish wave-uniform state (lanes 0-9 -> sh1, 10-19 -> sh2)
            int hbits = __float_as_int(hnew);
            #pragma unroll
            for (int k = 0; k < 20; ++k)
                S[k] = __int_as_float(__builtin_amdgcn_readlane(hbits, k));

            // output head: lane 20's raw dotR = blin + Wlin . h2_{i-2}
            const int t = (ib * 4 + u4) - 2;
            if (is20 && (unsigned)t < TT) op[t] = dotR;
        }
        xq = xqn;
    }
}

extern "C" void kernel_launch(void* const* d_in, const int* in_sizes, int n_in,
                              void* d_out, int out_size, void* d_ws, size_t ws_size,
                              hipStream_t stream) {
    const float* X    = (const float*)d_in[0];
    const float* Wih0 = (const float*)d_in[1];
    const float* Whh0 = (const float*)d_in[2];
    const float* bih0 = (const float*)d_in[3];
    const float* bhh0 = (const float*)d_in[4];
    const float* Wih1 = (const float*)d_in[5];
    const float* Whh1 = (const float*)d_in[6];
    const float* bih1 = (const float*)d_in[7];
    const float* bhh1 = (const float*)d_in[8];
    const float* Wlin = (const float*)d_in[9];
    const float* blin = (const float*)d_in[10];

    gru_wave_kernel<<<BB, 64, 0, stream>>>(X, Wih0, Whh0, bih0, bhh0,
                                           Wih1, Whh1, bih1, bhh1, Wlin, blin,
                                           (float*)d_out);
}

// Round 5
// 497.232 us; speedup vs baseline: 1.3234x; 1.1346x over previous
//
#include <hip/hip_runtime.h>

#define TT 2048
#define BB 1024
#define H  10

typedef float f2 __attribute__((ext_vector_type(2)));

// One wave64 per sequence. Self-dot design, packed-fp32 dots (v_pk_fma_f32).
// Lanes 0-9  : layer-0 gate lane, unit u=l      (uses S2 lower = h1_{i-1}, x_i)
// Lanes 10-19: layer-1 gate lane, unit u=l-10   (uses h1_{i-1} and h2_{i-2})
// Lane  20   : output head: dotR = blin + Wlin . h2_{i-2} -> out[t], t = i-2
// State: 10 f2 pairs S2[j] = {h[2j], h[2j+1]} over [h1(10); h2(10)], wave-uniform,
// rebuilt each step from 20 v_readlane. Weights per-lane packed f2 in VGPRs.
// Evidence R1-R4: wall ~ 4-6.6 cyc per VALU inst for a solo wave (issue-cadence
// bound); spills were irrelevant (R3->R4: VGPR 48->132, dur unchanged). So this
// round halves the dot instruction stream via packed math.
// Weights pre-scaled by -log2(e) (r,z) and +2*log2(e) (n):
//   r = rcp(1+2^dotR), z = rcp(1+2^dotZ)
//   q = fma(r, dotNh, dotNx); n = 1 - 2*rcp(1+2^q); h' = fma(z,h,fma(-z,n,n))

__device__ __forceinline__ float exp2f_fast(float a) { return __builtin_amdgcn_exp2f(a); }
__device__ __forceinline__ float rcpf_fast(float a)  { return __builtin_amdgcn_rcpf(a); }
__device__ __forceinline__ f2 fma2(f2 a, f2 b, f2 c) { return __builtin_elementwise_fma(a, b, c); }

__global__ __launch_bounds__(64)
__attribute__((amdgpu_waves_per_eu(1, 1)))
void gru_wave_kernel(
    const float* __restrict__ X,
    const float* __restrict__ Wih0, const float* __restrict__ Whh0,
    const float* __restrict__ bih0, const float* __restrict__ bhh0,
    const float* __restrict__ Wih1, const float* __restrict__ Whh1,
    const float* __restrict__ bih1, const float* __restrict__ bhh1,
    const float* __restrict__ Wlin, const float* __restrict__ blin,
    float* __restrict__ OUT)
{
    const int seq = blockIdx.x;
    const int l   = threadIdx.x;   // 0..63
    const float L2E = 1.44269504088896340736f;

    // packed per-lane weights over the 20-vector [h1(10); h2(10)]
    f2 wR2[10], wZ2[10], wN2[10], wX2[5];
    float bR = 0.f, bZ = 0.f, bNh = 0.f, bNx = 0.f;
    float wxr = 0.f, wxz = 0.f, wxn = 0.f;
    #pragma unroll
    for (int j = 0; j < 10; ++j) { wR2[j] = (f2)(0.f); wZ2[j] = (f2)(0.f); wN2[j] = (f2)(0.f); }
    #pragma unroll
    for (int j = 0; j < 5; ++j) wX2[j] = (f2)(0.f);

    if (l < 10) {                       // layer-0 gate lane, unit u = l
        const int u = l;
        #pragma unroll
        for (int k = 0; k < H; ++k) {
            wR2[k / 2][k % 2] = -L2E * Whh0[u * H + k];
            wZ2[k / 2][k % 2] = -L2E * Whh0[(10 + u) * H + k];
            wN2[k / 2][k % 2] = 2.f * L2E * Whh0[(20 + u) * H + k];
        }
        bR  = -L2E * (bih0[u] + bhh0[u]);
        bZ  = -L2E * (bih0[10 + u] + bhh0[10 + u]);
        bNh = 2.f * L2E * bhh0[20 + u];
        bNx = 2.f * L2E * bih0[20 + u];
        wxr = -L2E * Wih0[u];
        wxz = -L2E * Wih0[10 + u];
        wxn = 2.f * L2E * Wih0[20 + u];
    } else if (l < 20) {                // layer-1 gate lane, unit u = l-10
        const int u = l - 10;
        #pragma unroll
        for (int k = 0; k < H; ++k) {
            const int m = 10 + k;
            wR2[k / 2][k % 2] = -L2E * Wih1[u * H + k];
            wR2[m / 2][m % 2] = -L2E * Whh1[u * H + k];
            wZ2[k / 2][k % 2] = -L2E * Wih1[(10 + u) * H + k];
            wZ2[m / 2][m % 2] = -L2E * Whh1[(10 + u) * H + k];
            wN2[m / 2][m % 2] = 2.f * L2E * Whh1[(20 + u) * H + k];
            wX2[k / 2][k % 2] = 2.f * L2E * Wih1[(20 + u) * H + k];
        }
        bR  = -L2E * (bih1[u] + bhh1[u]);
        bZ  = -L2E * (bih1[10 + u] + bhh1[10 + u]);
        bNh = 2.f * L2E * bhh1[20 + u];
        bNx = 2.f * L2E * bih1[20 + u];
    } else if (l == 20) {               // output head (raw, unscaled)
        #pragma unroll
        for (int k = 0; k < H; ++k) {
            const int m = 10 + k;
            wR2[m / 2][m % 2] = Wlin[k];
        }
        bR = blin[0];
    }

    const bool isL1g = (l >= 10 && l < 20);

    // wave-uniform state pairs: S2[j] = {h[2j], h[2j+1]}, [h1; h2]
    f2 S2[10];
    #pragma unroll
    for (int j = 0; j < 10; ++j) S2[j] = (f2)(0.f);

    float hprev = 0.f;
    float o0 = 0.f, o1 = 0.f, o2 = 0.f, o3 = 0.f;

    const float* xp = X + seq * TT;
    float*       op = OUT + seq * TT;

    float4 xq = *(const float4*)xp;

    for (int ib = 0; ib < 513; ++ib) {
        int nb = 4 * (ib + 1);
        if (nb > TT - 4) nb = TT - 4;
        float4 xqn = *(const float4*)(xp + nb);
        float xs[4] = {xq.x, xq.y, xq.z, xq.w};
        #pragma unroll
        for (int u4 = 0; u4 < 4; ++u4) {
            const float x = xs[u4];

            // dotR: 10 pk ops in 2 chains + combine + scalar seed
            f2 ra = wR2[0] * S2[0];
            f2 rb = wR2[1] * S2[1];
            ra = fma2(wR2[2], S2[2], ra); rb = fma2(wR2[3], S2[3], rb);
            ra = fma2(wR2[4], S2[4], ra); rb = fma2(wR2[5], S2[5], rb);
            ra = fma2(wR2[6], S2[6], ra); rb = fma2(wR2[7], S2[7], rb);
            ra = fma2(wR2[8], S2[8], ra); rb = fma2(wR2[9], S2[9], rb);
            f2 rs = ra + rb;
            float dotR = (rs.x + rs.y) + fmaf(wxr, x, bR);

            // dotZ
            f2 za = wZ2[0] * S2[0];
            f2 zb = wZ2[1] * S2[1];
            za = fma2(wZ2[2], S2[2], za); zb = fma2(wZ2[3], S2[3], zb);
            za = fma2(wZ2[4], S2[4], za); zb = fma2(wZ2[5], S2[5], zb);
            za = fma2(wZ2[6], S2[6], za); zb = fma2(wZ2[7], S2[7], zb);
            za = fma2(wZ2[8], S2[8], za); zb = fma2(wZ2[9], S2[9], zb);
            f2 zs = za + zb;
            float dotZ = (zs.x + zs.y) + fmaf(wxz, x, bZ);

            // dotNh
            f2 na = wN2[0] * S2[0];
            f2 nb2 = wN2[1] * S2[1];
            na = fma2(wN2[2], S2[2], na); nb2 = fma2(wN2[3], S2[3], nb2);
            na = fma2(wN2[4], S2[4], na); nb2 = fma2(wN2[5], S2[5], nb2);
            na = fma2(wN2[6], S2[6], na); nb2 = fma2(wN2[7], S2[7], nb2);
            na = fma2(wN2[8], S2[8], na); nb2 = fma2(wN2[9], S2[9], nb2);
            f2 ns = na + nb2;
            float dotNh = (ns.x + ns.y) + bNh;

            // dotNx (over h1 pairs only; x-term is the seed for L0)
            f2 qa = wX2[0] * S2[0];
            f2 qb = wX2[1] * S2[1];
            qa = fma2(wX2[2], S2[2], qa); qb = fma2(wX2[3], S2[3], qb);
            qa = fma2(wX2[4], S2[4], qa);
            f2 qs = qa + qb;
            float dotNx = (qs.x + qs.y) + fmaf(wxn, x, bNx);

            // gates (pre-scaled dots)
            float r = rcpf_fast(1.0f + exp2f_fast(dotR));
            float z = rcpf_fast(1.0f + exp2f_fast(dotZ));
            float q = fmaf(r, dotNh, dotNx);
            float n = fmaf(-2.0f, rcpf_fast(1.0f + exp2f_fast(q)), 1.0f);
            float hnew = fmaf(z, hprev, fmaf(-z, n, n));

            // iteration 0: L1 gate lanes would publish garbage h2_{-1}; force 0
            if (ib == 0 && u4 == 0) { if (isL1g) hnew = 0.f; }
            hprev = hnew;

            // publish wave-uniform state pairs (20 readlanes)
            int hbits = __float_as_int(hnew);
            #pragma unroll
            for (int j = 0; j < 10; ++j) {
                S2[j][0] = __int_as_float(__builtin_amdgcn_readlane(hbits, 2 * j));
                S2[j][1] = __int_as_float(__builtin_amdgcn_readlane(hbits, 2 * j + 1));
            }

            // collect head output (lane 20's dotR), t = 4*ib + u4 - 2
            if (u4 == 0) o0 = dotR;
            else if (u4 == 1) o1 = dotR;
            else if (u4 == 2) o2 = dotR;
            else o3 = dotR;
        }
        // batched head stores (lane 20 only), two dwordx2 per 4-step block
        if (l == 20) {
            if (ib == 0) {
                *(f2*)(op + 0) = (f2){o2, o3};              // t = 0,1
            } else if (ib < 512) {
                *(f2*)(op + 4 * ib - 2) = (f2){o0, o1};     // t = 4ib-2, 4ib-1
                *(f2*)(op + 4 * ib)     = (f2){o2, o3};     // t = 4ib,   4ib+1
            } else {
                *(f2*)(op + 2046) = (f2){o0, o1};           // t = 2046, 2047
            }
        }
        xq = xqn;
    }
}

extern "C" void kernel_launch(void* const* d_in, const int* in_sizes, int n_in,
                              void* d_out, int out_size, void* d_ws, size_t ws_size,
                              hipStream_t stream) {
    const float* X    = (const float*)d_in[0];
    const float* Wih0 = (const float*)d_in[1];
    const float* Whh0 = (const float*)d_in[2];
    const float* bih0 = (const float*)d_in[3];
    const float* bhh0 = (const float*)d_in[4];
    const float* Wih1 = (const float*)d_in[5];
    const float* Whh1 = (const float*)d_in[6];
    const float* bih1 = (const float*)d_in[7];
    const float* bhh1 = (const float*)d_in[8];
    const float* Wlin = (const float*)d_in[9];
    const float* blin = (const float*)d_in[10];

    gru_wave_kernel<<<BB, 64, 0, stream>>>(X, Wih0, Whh0, bih0, bhh0,
                                           Wih1, Whh1, bih1, bhh1, Wlin, blin,
                                           (float*)d_out);
}